// Round 1
// 986.632 us; speedup vs baseline: 1.5120x; 1.5120x over previous
//
#include <hip/hip_runtime.h>
#include <math.h>

typedef __attribute__((ext_vector_type(8))) short bf16x8;
typedef __attribute__((ext_vector_type(4))) float f32x4;

constexpr int NB = 512;
constexpr int NS = 140;
constexpr int NH = 512;
constexpr int NE = 256;
constexpr int NV = 1000;
constexpr int NVP = 1024;   // padded vocab
constexpr int NT = 21;
constexpr int ND = 7;
constexpr int DL = 20;
constexpr int SOS = 2;
constexpr int LSTR = NT + 1;
constexpr int NROW = NT * NB;       // 10752 batched (t,b) rows

__device__ __forceinline__ unsigned short f2bf(float f) {
  union { float f; unsigned u; } v; v.f = f;
  unsigned r = v.u + 0x7fffu + ((v.u >> 16) & 1u);
  return (unsigned short)(r >> 16);
}
__device__ __forceinline__ float bf2f(unsigned short h) {
  union { unsigned u; float f; } v; v.u = ((unsigned)h) << 16;
  return v.f;
}

// ---------------------------------------------------------------------------
// 64x64 MFMA tile body, double-buffered LDS (ONE barrier per K-chunk).
// A16: bf16 A. EPI: 0 none, 1 +bias (guarded col<NV), 2 tanh. OUT16: bf16 out.
// ---------------------------------------------------------------------------
template<int A16, int EPI, int OUT16>
__device__ __forceinline__ void gemm_body(
    const float* __restrict__ Af, const unsigned short* __restrict__ Ah,
    const unsigned short* __restrict__ Bt, const float* __restrict__ bias,
    float* __restrict__ C, unsigned short* __restrict__ C16,
    int K, int lda, int ldc, int bx, int by,
    unsigned short* As, unsigned short* Bs)
{
  const int tid = threadIdx.x;
  const int rowBase = by * 64, colBase = bx * 64;
  const int wave = tid >> 6, lane = tid & 63, quad = lane >> 4, l15 = lane & 15;
  const int rw = (wave & 1) * 32, cw = (wave >> 1) * 32;

  f32x4 acc[2][2];
#pragma unroll
  for (int i = 0; i < 2; ++i)
#pragma unroll
    for (int j = 0; j < 2; ++j)
#pragma unroll
      for (int r = 0; r < 4; ++r) acc[i][j][r] = 0.f;

  const int ar = tid >> 2;
  const int kq = (tid & 3) * 8;
  const float* aptrf = nullptr;
  const unsigned short* aptrh = nullptr;
  if (A16) aptrh = Ah + (size_t)(rowBase + ar) * lda + kq;
  else     aptrf = Af + (size_t)(rowBase + ar) * lda + kq;
  const unsigned short* bptr = Bt + (size_t)(colBase + ar) * K + kq;
  unsigned short* asd = &As[ar * 40 + kq];
  unsigned short* bsd = &Bs[ar * 40 + kq];

  float4 x0, x1;
  uint4 av;
  if (A16) {
    av = *(const uint4*)aptrh;
  } else {
    x0 = *(const float4*)aptrf; x1 = *(const float4*)(aptrf + 4);
  }
  uint4 bv = *(const uint4*)bptr;

  int cur = 0;
  for (int k0 = 0; k0 < K; k0 += 32) {
    uint4 aw;
    if (A16) {
      aw = av;
    } else {
      aw.x = (unsigned)f2bf(x0.x) | ((unsigned)f2bf(x0.y) << 16);
      aw.y = (unsigned)f2bf(x0.z) | ((unsigned)f2bf(x0.w) << 16);
      aw.z = (unsigned)f2bf(x1.x) | ((unsigned)f2bf(x1.y) << 16);
      aw.w = (unsigned)f2bf(x1.z) | ((unsigned)f2bf(x1.w) << 16);
    }
    *(uint4*)(asd + cur * 2560) = aw;
    *(uint4*)(bsd + cur * 2560) = bv;

    const int kn = k0 + 32;
    if (kn < K) {
      if (A16) {
        av = *(const uint4*)(aptrh + kn);
      } else {
        x0 = *(const float4*)(aptrf + kn);
        x1 = *(const float4*)(aptrf + kn + 4);
      }
      bv = *(const uint4*)(bptr + kn);
    }
    __syncthreads();

    const unsigned short* Ab = As + cur * 2560;
    const unsigned short* Bb = Bs + cur * 2560;
    const bf16x8 af0 = *(const bf16x8*)&Ab[(rw + l15) * 40 + quad * 8];
    const bf16x8 af1 = *(const bf16x8*)&Ab[(rw + 16 + l15) * 40 + quad * 8];
    const bf16x8 bf0 = *(const bf16x8*)&Bb[(cw + l15) * 40 + quad * 8];
    const bf16x8 bf1 = *(const bf16x8*)&Bb[(cw + 16 + l15) * 40 + quad * 8];
    acc[0][0] = __builtin_amdgcn_mfma_f32_16x16x32_bf16(af0, bf0, acc[0][0], 0, 0, 0);
    acc[0][1] = __builtin_amdgcn_mfma_f32_16x16x32_bf16(af0, bf1, acc[0][1], 0, 0, 0);
    acc[1][0] = __builtin_amdgcn_mfma_f32_16x16x32_bf16(af1, bf0, acc[1][0], 0, 0, 0);
    acc[1][1] = __builtin_amdgcn_mfma_f32_16x16x32_bf16(af1, bf1, acc[1][1], 0, 0, 0);
    cur ^= 1;
  }

#pragma unroll
  for (int i = 0; i < 2; ++i) {
    const int grow = rowBase + rw + 16 * i + quad * 4;
#pragma unroll
    for (int j = 0; j < 2; ++j) {
      const int gcol = colBase + cw + 16 * j + l15;
#pragma unroll
      for (int r = 0; r < 4; ++r) {
        float vo = acc[i][j][r];
        if (EPI == 1) vo += (gcol < NV) ? bias[gcol] : 0.f;
        if (EPI == 2) vo = tanhf(vo);
        if (OUT16) C16[(size_t)(grow + r) * ldc + gcol] = f2bf(vo);
        else       C[(size_t)(grow + r) * ldc + gcol] = vo;
      }
    }
  }
}

template<int A16, int EPI, int OUT16>
__global__ __launch_bounds__(256) void gemm_k(
    const float* __restrict__ Af, const unsigned short* __restrict__ Ah,
    const unsigned short* __restrict__ Bt, const float* __restrict__ bias,
    float* __restrict__ C, unsigned short* __restrict__ C16,
    int K, int lda, int ldc)
{
  __shared__ unsigned short As[2 * 64 * 40];
  __shared__ unsigned short Bs[2 * 64 * 40];
  gemm_body<A16, EPI, OUT16>(Af, Ah, Bt, bias, C, C16, K, lda, ldc,
                             blockIdx.x, blockIdx.y, As, Bs);
}

// ---------------------------------------------------------------------------
// Gi precompute: all 21 steps of emb[dec_t] @ W_ih^T, bf16 out. 2D grid.
// ---------------------------------------------------------------------------
__global__ __launch_bounds__(256) void gemm_gather(
    const float* __restrict__ emb, const unsigned short* __restrict__ Wiht,
    unsigned short* __restrict__ Gi, const int* __restrict__ label)
{
  __shared__ unsigned short As[64 * 40];
  __shared__ unsigned short Bs[64 * 40];
  const int tid = threadIdx.x;
  const int rowBase = blockIdx.y * 64, colBase = blockIdx.x * 64;
  const int wave = tid >> 6, lane = tid & 63, quad = lane >> 4, l15 = lane & 15;
  const int rw = (wave & 1) * 32, cw = (wave >> 1) * 32;
  const int K = 256;

  f32x4 acc[2][2];
#pragma unroll
  for (int i = 0; i < 2; ++i)
#pragma unroll
    for (int j = 0; j < 2; ++j)
#pragma unroll
      for (int r = 0; r < 4; ++r) acc[i][j][r] = 0.f;

  const int ar = tid >> 2;
  const int kq = (tid & 3) * 8;
  const int aRowG = rowBase + ar;
  const int t = aRowG >> 9;
  const int b = aRowG & 511;
  const int dec = (t == 0) ? SOS : label[b * LSTR + (t - 1)];
  const float* aptr = emb + (size_t)dec * NE + kq;
  const unsigned short* bptr = Wiht + (size_t)(colBase + ar) * K + kq;
  unsigned short* asd = &As[ar * 40 + kq];
  unsigned short* bsd = &Bs[ar * 40 + kq];

  float4 x0 = *(const float4*)aptr;
  float4 x1 = *(const float4*)(aptr + 4);
  uint4 bv = *(const uint4*)bptr;

  for (int k0 = 0; k0 < K; k0 += 32) {
    uint4 aw;
    aw.x = (unsigned)f2bf(x0.x) | ((unsigned)f2bf(x0.y) << 16);
    aw.y = (unsigned)f2bf(x0.z) | ((unsigned)f2bf(x0.w) << 16);
    aw.z = (unsigned)f2bf(x1.x) | ((unsigned)f2bf(x1.y) << 16);
    aw.w = (unsigned)f2bf(x1.z) | ((unsigned)f2bf(x1.w) << 16);
    *(uint4*)asd = aw;
    *(uint4*)bsd = bv;
    __syncthreads();
    const int kn = k0 + 32;
    if (kn < K) {
      x0 = *(const float4*)(aptr + kn);
      x1 = *(const float4*)(aptr + kn + 4);
      bv = *(const uint4*)(bptr + kn);
    }
    const bf16x8 af0 = *(const bf16x8*)&As[(rw + l15) * 40 + quad * 8];
    const bf16x8 af1 = *(const bf16x8*)&As[(rw + 16 + l15) * 40 + quad * 8];
    const bf16x8 bf0 = *(const bf16x8*)&Bs[(cw + l15) * 40 + quad * 8];
    const bf16x8 bf1 = *(const bf16x8*)&Bs[(cw + 16 + l15) * 40 + quad * 8];
    acc[0][0] = __builtin_amdgcn_mfma_f32_16x16x32_bf16(af0, bf0, acc[0][0], 0, 0, 0);
    acc[0][1] = __builtin_amdgcn_mfma_f32_16x16x32_bf16(af0, bf1, acc[0][1], 0, 0, 0);
    acc[1][0] = __builtin_amdgcn_mfma_f32_16x16x32_bf16(af1, bf0, acc[1][0], 0, 0, 0);
    acc[1][1] = __builtin_amdgcn_mfma_f32_16x16x32_bf16(af1, bf1, acc[1][1], 0, 0, 0);
    __syncthreads();
  }

#pragma unroll
  for (int i = 0; i < 2; ++i) {
    const int grow = rowBase + rw + 16 * i + quad * 4;
#pragma unroll
    for (int j = 0; j < 2; ++j) {
      const int gcol = colBase + cw + 16 * j + l15;
#pragma unroll
      for (int r = 0; r < 4; ++r)
        Gi[(size_t)(grow + r) * 1536 + gcol] = f2bf(acc[i][j][r]);
    }
  }
}

// ---------------------------------------------------------------------------
// GRU elementwise: h_{t+1} = GRU(Gi_t, gh_t, h_t).  grid 1024 x 256.
// ---------------------------------------------------------------------------
__global__ __launch_bounds__(256) void gru_step(
    const float* __restrict__ gh, const unsigned short* __restrict__ gi,
    const float* __restrict__ b_ih, const float* __restrict__ b_hh,
    const float* __restrict__ hR, float* __restrict__ hW)
{
  const int idx = blockIdx.x * 256 + threadIdx.x;
  const int b = idx >> 9, j = idx & (NH - 1);
  const unsigned short* gib = gi + (size_t)b * 1536;
  const float* ghb = gh + (size_t)b * 1536;
  const float ir  = bf2f(gib[j]) + b_ih[j];
  const float iz  = bf2f(gib[NH + j]) + b_ih[NH + j];
  const float in_ = bf2f(gib[2 * NH + j]) + b_ih[2 * NH + j];
  const float hr  = ghb[j] + b_hh[j];
  const float hz  = ghb[NH + j] + b_hh[NH + j];
  const float hn_ = ghb[2 * NH + j] + b_hh[2 * NH + j];
  const float rg = 1.f / (1.f + expf(-(ir + hr)));
  const float zg = 1.f / (1.f + expf(-(iz + hz)));
  const float ng = tanhf(in_ + rg * hn_);
  hW[idx] = (1.f - zg) * ng + zg * hR[idx];
}

// ---------------------------------------------------------------------------
// Batched day attention: one block per (b,d); enc tile staged in LDS once
// (f32), loop over all 21 timesteps.  week out bf16 [t][b][d][h].
// ---------------------------------------------------------------------------
__global__ __launch_bounds__(256) void day_attn(
    const float* __restrict__ enc, const int* __restrict__ numpairs,
    const float* __restrict__ U, unsigned short* __restrict__ week)
{
  __shared__ float es[DL * NH];       // 40 KB
  __shared__ float scD[DL];
  __shared__ float wdD[DL];
  __shared__ int   msk[DL];
  const int tid = threadIdx.x;
  const int wave = tid >> 6, lane = tid & 63;
  const int b = blockIdx.x / ND, d = blockIdx.x % ND;

  const float4* ep = (const float4*)(enc + ((size_t)b * NS + d * DL) * NH);
  float4* dst = (float4*)es;
  for (int i = tid; i < DL * NH / 4; i += 256) dst[i] = ep[i];
  if (tid < DL) msk[tid] = numpairs[b * NS + d * DL + tid];
  __syncthreads();

  for (int t = 0; t < NT; ++t) {
    const float* u = U + ((size_t)t * NB + b) * NH + lane * 8;
    const float4 ua = *(const float4*)u;
    const float4 ub = *(const float4*)(u + 4);
#pragma unroll
    for (int si = 0; si < 5; ++si) {
      const int s = wave * 5 + si;
      const float* er = es + s * NH + lane * 8;
      const float4 e0 = *(const float4*)er;
      const float4 e1 = *(const float4*)(er + 4);
      float p = e0.x * ua.x + e0.y * ua.y + e0.z * ua.z + e0.w * ua.w
              + e1.x * ub.x + e1.y * ub.y + e1.z * ub.z + e1.w * ub.w;
#pragma unroll
      for (int off = 32; off; off >>= 1) p += __shfl_down(p, off);
      if (lane == 0) scD[s] = p;
    }
    __syncthreads();
    if (wave == 0) {
      float v = -1e30f;
      if (lane < DL) {
        v = scD[lane];
        if (msk[lane] == 0) v = -1e9f;
      }
      float mx = v;
#pragma unroll
      for (int off = 32; off; off >>= 1) mx = fmaxf(mx, __shfl_xor(mx, off));
      const float e = (lane < DL) ? expf(v - mx) : 0.f;
      float sm = e;
#pragma unroll
      for (int off = 32; off; off >>= 1) sm += __shfl_xor(sm, off);
      if (lane < DL) wdD[lane] = e / sm;
    }
    __syncthreads();
    float a0 = 0.f, a1 = 0.f;
#pragma unroll
    for (int s = 0; s < DL; ++s) {
      const float w = wdD[s];
      const float2 ev = *(const float2*)(es + s * NH + tid * 2);
      a0 += w * ev.x;
      a1 += w * ev.y;
    }
    const unsigned pack = (unsigned)f2bf(a0) | ((unsigned)f2bf(a1) << 16);
    *(unsigned*)(week + (((size_t)t * NB + b) * ND + d) * NH + tid * 2) = pack;
    __syncthreads();
  }
}

// ---------------------------------------------------------------------------
// Batched week attention + ctx + concat.  One block = (t, 16 b's).
// concat row r = t*NB+b: [h_{t+1} | ctx] bf16.
// ---------------------------------------------------------------------------
__global__ __launch_bounds__(256) void wk_ctx(
    const float* __restrict__ U, const unsigned short* __restrict__ week,
    const float* __restrict__ H, unsigned short* __restrict__ concat)
{
  __shared__ float scS[16 * ND];
  __shared__ float awS[16 * ND];
  const int tid = threadIdx.x;
  const int t = blockIdx.x >> 5;
  const int grp = blockIdx.x & 31;
  const int b16 = tid >> 4, k16 = tid & 15;
  const int b = grp * 16 + b16;
  const float* vp = U + ((size_t)(t + 1) * NB + b) * NH + k16 * 32;
  const size_t wrow = ((size_t)t * NB + b) * ND;

  for (int d = 0; d < ND; ++d) {
    const unsigned short* wp = week + (wrow + d) * NH + k16 * 32;
    float p = 0.f;
#pragma unroll
    for (int q = 0; q < 8; ++q) {
      const float4 a = *(const float4*)(vp + q * 4);
      const ushort4 wv = *(const ushort4*)(wp + q * 4);
      p += a.x * bf2f(wv.x) + a.y * bf2f(wv.y) + a.z * bf2f(wv.z) + a.w * bf2f(wv.w);
    }
    p += __shfl_down(p, 8); p += __shfl_down(p, 4);
    p += __shfl_down(p, 2); p += __shfl_down(p, 1);
    if (k16 == 0) scS[b16 * ND + d] = p;
  }
  __syncthreads();
  if (tid < 16) {
    float s[ND], mx = -1e30f;
    for (int d = 0; d < ND; ++d) { s[d] = scS[tid * ND + d]; mx = fmaxf(mx, s[d]); }
    float sum = 0.f;
    for (int d = 0; d < ND; ++d) { float e = expf(s[d] - mx); s[d] = e; sum += e; }
    const float inv = 1.f / sum;
    for (int d = 0; d < ND; ++d) awS[tid * ND + d] = s[d] * inv;
  }
  __syncthreads();

  const int c0 = k16 * 32;
  const float* hp = H + ((size_t)(t + 1) * NB + b) * NH + c0;
  float aw[ND];
#pragma unroll
  for (int d = 0; d < ND; ++d) aw[d] = awS[b16 * ND + d];
  unsigned short* crow = concat + ((size_t)t * NB + b) * 1024;
#pragma unroll
  for (int q = 0; q < 8; ++q) {
    const int c = c0 + q * 4;
    const float4 hv = *(const float4*)(hp + q * 4);
    ushort4 hs;
    hs.x = f2bf(hv.x); hs.y = f2bf(hv.y); hs.z = f2bf(hv.z); hs.w = f2bf(hv.w);
    *(ushort4*)(crow + c) = hs;
    float4 cv = make_float4(0.f, 0.f, 0.f, 0.f);
#pragma unroll
    for (int d = 0; d < ND; ++d) {
      const ushort4 wv = *(const ushort4*)(week + (wrow + d) * NH + c);
      cv.x += aw[d] * bf2f(wv.x); cv.y += aw[d] * bf2f(wv.y);
      cv.z += aw[d] * bf2f(wv.z); cv.w += aw[d] * bf2f(wv.w);
    }
    ushort4 cs;
    cs.x = f2bf(cv.x); cs.y = f2bf(cv.y); cs.z = f2bf(cv.z); cs.w = f2bf(cv.w);
    *(ushort4*)(crow + 512 + c) = cs;
  }
}

// ---------------------------------------------------------------------------
// Single-pass log_softmax: row resident in registers (4 floats/thread).
// Row r = t*NB+b  ->  out[b, t, :].
// ---------------------------------------------------------------------------
__global__ __launch_bounds__(256) void lsm_k(
    const float* __restrict__ logits, float* __restrict__ out)
{
  __shared__ float red[8];
  const int tid = threadIdx.x;
  const int wave = tid >> 6, lane = tid & 63;
  const int r = blockIdx.x;
  const int t = r >> 9, b = r & (NB - 1);
  const float* row = logits + (size_t)r * NVP;
  float v[4];
  float mx = -1e30f;
#pragma unroll
  for (int k = 0; k < 4; ++k) {
    const int c = tid + k * 256;
    v[k] = row[c];
    if (c < NV) mx = fmaxf(mx, v[k]);
  }
#pragma unroll
  for (int off = 32; off; off >>= 1) mx = fmaxf(mx, __shfl_xor(mx, off));
  if (lane == 0) red[wave] = mx;
  __syncthreads();
  mx = fmaxf(fmaxf(red[0], red[1]), fmaxf(red[2], red[3]));
  float s = 0.f;
#pragma unroll
  for (int k = 0; k < 4; ++k) {
    const int c = tid + k * 256;
    if (c < NV) s += expf(v[k] - mx);
  }
#pragma unroll
  for (int off = 32; off; off >>= 1) s += __shfl_xor(s, off);
  if (lane == 0) red[4 + wave] = s;
  __syncthreads();
  const float lse = mx + logf(red[4] + red[5] + red[6] + red[7]);
  float* orow = out + ((size_t)b * NT + t) * NV;
#pragma unroll
  for (int k = 0; k < 4; ++k) {
    const int c = tid + k * 256;
    if (c < NV) orow[c] = v[k] - lse;
  }
}

__global__ void write_last(const int* __restrict__ label, float* __restrict__ out2)
{
  const int b = blockIdx.x * 256 + threadIdx.x;
  if (b < NB) out2[b] = (float)label[b * LSTR + (NT - 1)];
}

// Wat[n][k] = Wa[k][n]  (bf16, (n,k) layout for gemm B)
__global__ __launch_bounds__(256) void pack_wat(
    const float* __restrict__ Wa, unsigned short* __restrict__ Wat)
{
  const int idx = blockIdx.x * 256 + threadIdx.x;
  const int n = idx >> 9, k = idx & 511;
  Wat[idx] = f2bf(Wa[k * NH + n]);
}

__global__ __launch_bounds__(256) void cast4(
    const float4* __restrict__ in, ushort4* __restrict__ out, int n4)
{
  const int i = blockIdx.x * 256 + threadIdx.x;
  if (i < n4) {
    const float4 x = in[i];
    ushort4 r;
    r.x = f2bf(x.x); r.y = f2bf(x.y); r.z = f2bf(x.z); r.w = f2bf(x.w);
    out[i] = r;
  }
}

extern "C" void kernel_launch(void* const* d_in, const int* in_sizes, int n_in,
                              void* d_out, int out_size, void* d_ws, size_t ws_size,
                              hipStream_t stream)
{
  const float* enc_h  = (const float*)d_in[0];
  const float* enc    = (const float*)d_in[1];
  const int*   label  = (const int*)d_in[2];
  const int*   numprs = (const int*)d_in[3];
  const float* emb    = (const float*)d_in[4];
  const float* W_ih   = (const float*)d_in[5];
  const float* W_hh   = (const float*)d_in[6];
  const float* b_ih   = (const float*)d_in[7];
  const float* b_hh   = (const float*)d_in[8];
  const float* Wa     = (const float*)d_in[9];
  const float* wa_W   = (const float*)d_in[10];
  const float* fc_W   = (const float*)d_in[11];
  const float* fc_b   = (const float*)d_in[12];
  float* out = (float*)d_out;

  float* f = (float*)d_ws;
  float* H_all   = f; f += (size_t)(NT + 1) * NB * NH;   // 22 hidden states, f32
  float* gh      = f; f += (size_t)NB * 1536;            // h @ W_hh^T scratch
  float* U_all   = f; f += (size_t)(NT + 1) * NB * NH;   // h_t @ Wa, all t
  float* logitsW = f; f += (size_t)NROW * NVP;
  unsigned short* us = (unsigned short*)f;
  unsigned short* Whh16  = us; us += (size_t)1536 * 512;
  unsigned short* Wat    = us; us += (size_t)512 * 512;
  unsigned short* W3t    = us; us += (size_t)512 * 1024;
  unsigned short* W4t    = us; us += (size_t)NVP * 512;
  unsigned short* Wiht   = us; us += (size_t)1536 * 256;
  unsigned short* Gi     = us; us += (size_t)NT * NB * 1536;
  unsigned short* week   = us; us += (size_t)NT * NB * ND * NH;
  unsigned short* concatW= us; us += (size_t)NROW * 1024;
  unsigned short* aBuf   = us; us += (size_t)NROW * 512;

  const dim3 blk(256);

  hipMemcpyAsync(H_all, enc_h, (size_t)NB * NH * sizeof(float),
                 hipMemcpyDeviceToDevice, stream);

  // --- setup: weight casts + Gi precompute ---
  cast4<<<dim3(1536 * 512 / 4 / 256), blk, 0, stream>>>(
      (const float4*)W_hh, (ushort4*)Whh16, 1536 * 512 / 4);
  pack_wat<<<dim3(512 * 512 / 256), blk, 0, stream>>>(Wa, Wat);
  cast4<<<dim3(512 * 1024 / 4 / 256), blk, 0, stream>>>(
      (const float4*)wa_W, (ushort4*)W3t, 512 * 1024 / 4);
  cast4<<<dim3((NV * 512 / 4 + 255) / 256), blk, 0, stream>>>(
      (const float4*)fc_W, (ushort4*)W4t, NV * 512 / 4);
  hipMemsetAsync(W4t + (size_t)NV * 512, 0, (size_t)(NVP - NV) * 512 * 2, stream);
  cast4<<<dim3(1536 * 256 / 4 / 256), blk, 0, stream>>>(
      (const float4*)W_ih, (ushort4*)Wiht, 1536 * 256 / 4);
  gemm_gather<<<dim3(24, NT * 8), blk, 0, stream>>>(emb, Wiht, Gi, label);

  // --- recurrent phase: only the GRU chain (the true serial dependency) ---
  for (int t = 0; t < NT; ++t) {
    gemm_k<0, 0, 0><<<dim3(24, 8), blk, 0, stream>>>(
        H_all + (size_t)t * NB * NH, nullptr, Whh16, nullptr,
        gh, nullptr, 512, 512, 1536);
    gru_step<<<dim3(NB * NH / 256), blk, 0, stream>>>(
        gh, Gi + (size_t)t * NB * 1536, b_ih, b_hh,
        H_all + (size_t)t * NB * NH, H_all + (size_t)(t + 1) * NB * NH);
  }

  // --- batched tail: everything independent given H_all ---
  // U_all[t] = h_t @ Wa for all 22 states (day attn uses t, week attn t+1)
  gemm_k<0, 0, 0><<<dim3(8, (NT + 1) * 8), blk, 0, stream>>>(
      H_all, nullptr, Wat, nullptr, U_all, nullptr, 512, 512, 512);
  day_attn<<<dim3(NB * ND), blk, 0, stream>>>(enc, numprs, U_all, week);
  wk_ctx<<<dim3(NT * 32), blk, 0, stream>>>(U_all, week, H_all, concatW);
  gemm_k<1, 2, 1><<<dim3(8, NROW / 64), blk, 0, stream>>>(
      nullptr, concatW, W3t, nullptr, nullptr, aBuf, 1024, 1024, 512);
  gemm_k<1, 1, 0><<<dim3(16, NROW / 64), blk, 0, stream>>>(
      nullptr, aBuf, W4t, fc_b, logitsW, nullptr, 512, 512, NVP);
  lsm_k<<<dim3(NROW), blk, 0, stream>>>(logitsW, out);
  write_last<<<dim3(2), blk, 0, stream>>>(label, out + (size_t)NB * NT * NV);
}

// Round 2
// 914.188 us; speedup vs baseline: 1.6318x; 1.0792x over previous
//
#include <hip/hip_runtime.h>
#include <math.h>

typedef __attribute__((ext_vector_type(8))) short bf16x8;
typedef __attribute__((ext_vector_type(4))) float f32x4;

constexpr int NB = 512;
constexpr int NS = 140;
constexpr int NH = 512;
constexpr int NE = 256;
constexpr int NV = 1000;
constexpr int NVP = 1024;   // padded vocab
constexpr int NT = 21;
constexpr int ND = 7;
constexpr int DL = 20;
constexpr int SOS = 2;
constexpr int LSTR = NT + 1;
constexpr int NROW = NT * NB;       // 10752 batched (t,b) rows

__device__ __forceinline__ unsigned short f2bf(float f) {
  union { float f; unsigned u; } v; v.f = f;
  unsigned r = v.u + 0x7fffu + ((v.u >> 16) & 1u);
  return (unsigned short)(r >> 16);
}
__device__ __forceinline__ float bf2f(unsigned short h) {
  union { unsigned u; float f; } v; v.u = ((unsigned)h) << 16;
  return v.f;
}
__device__ __forceinline__ void unp8(uint4 v, float* o) {
  o[0] = bf2f((unsigned short)(v.x & 0xffffu)); o[1] = bf2f((unsigned short)(v.x >> 16));
  o[2] = bf2f((unsigned short)(v.y & 0xffffu)); o[3] = bf2f((unsigned short)(v.y >> 16));
  o[4] = bf2f((unsigned short)(v.z & 0xffffu)); o[5] = bf2f((unsigned short)(v.z >> 16));
  o[6] = bf2f((unsigned short)(v.w & 0xffffu)); o[7] = bf2f((unsigned short)(v.w >> 16));
}

// ---------------------------------------------------------------------------
// 64x64 MFMA tile body, double-buffered LDS (ONE barrier per K-chunk).
// A16: bf16 A. EPI: 0 none, 1 +bias (guarded col<NV), 2 tanh. OUT16: bf16 out.
// ---------------------------------------------------------------------------
template<int A16, int EPI, int OUT16>
__device__ __forceinline__ void gemm_body(
    const float* __restrict__ Af, const unsigned short* __restrict__ Ah,
    const unsigned short* __restrict__ Bt, const float* __restrict__ bias,
    float* __restrict__ C, unsigned short* __restrict__ C16,
    int K, int lda, int ldc, int bx, int by,
    unsigned short* As, unsigned short* Bs)
{
  const int tid = threadIdx.x;
  const int rowBase = by * 64, colBase = bx * 64;
  const int wave = tid >> 6, lane = tid & 63, quad = lane >> 4, l15 = lane & 15;
  const int rw = (wave & 1) * 32, cw = (wave >> 1) * 32;

  f32x4 acc[2][2];
#pragma unroll
  for (int i = 0; i < 2; ++i)
#pragma unroll
    for (int j = 0; j < 2; ++j)
#pragma unroll
      for (int r = 0; r < 4; ++r) acc[i][j][r] = 0.f;

  const int ar = tid >> 2;
  const int kq = (tid & 3) * 8;
  const float* aptrf = nullptr;
  const unsigned short* aptrh = nullptr;
  if (A16) aptrh = Ah + (size_t)(rowBase + ar) * lda + kq;
  else     aptrf = Af + (size_t)(rowBase + ar) * lda + kq;
  const unsigned short* bptr = Bt + (size_t)(colBase + ar) * K + kq;
  unsigned short* asd = &As[ar * 40 + kq];
  unsigned short* bsd = &Bs[ar * 40 + kq];

  float4 x0, x1;
  uint4 av;
  if (A16) {
    av = *(const uint4*)aptrh;
  } else {
    x0 = *(const float4*)aptrf; x1 = *(const float4*)(aptrf + 4);
  }
  uint4 bv = *(const uint4*)bptr;

  int cur = 0;
  for (int k0 = 0; k0 < K; k0 += 32) {
    uint4 aw;
    if (A16) {
      aw = av;
    } else {
      aw.x = (unsigned)f2bf(x0.x) | ((unsigned)f2bf(x0.y) << 16);
      aw.y = (unsigned)f2bf(x0.z) | ((unsigned)f2bf(x0.w) << 16);
      aw.z = (unsigned)f2bf(x1.x) | ((unsigned)f2bf(x1.y) << 16);
      aw.w = (unsigned)f2bf(x1.z) | ((unsigned)f2bf(x1.w) << 16);
    }
    *(uint4*)(asd + cur * 2560) = aw;
    *(uint4*)(bsd + cur * 2560) = bv;

    const int kn = k0 + 32;
    if (kn < K) {
      if (A16) {
        av = *(const uint4*)(aptrh + kn);
      } else {
        x0 = *(const float4*)(aptrf + kn);
        x1 = *(const float4*)(aptrf + kn + 4);
      }
      bv = *(const uint4*)(bptr + kn);
    }
    __syncthreads();

    const unsigned short* Ab = As + cur * 2560;
    const unsigned short* Bb = Bs + cur * 2560;
    const bf16x8 af0 = *(const bf16x8*)&Ab[(rw + l15) * 40 + quad * 8];
    const bf16x8 af1 = *(const bf16x8*)&Ab[(rw + 16 + l15) * 40 + quad * 8];
    const bf16x8 bf0 = *(const bf16x8*)&Bb[(cw + l15) * 40 + quad * 8];
    const bf16x8 bf1 = *(const bf16x8*)&Bb[(cw + 16 + l15) * 40 + quad * 8];
    acc[0][0] = __builtin_amdgcn_mfma_f32_16x16x32_bf16(af0, bf0, acc[0][0], 0, 0, 0);
    acc[0][1] = __builtin_amdgcn_mfma_f32_16x16x32_bf16(af0, bf1, acc[0][1], 0, 0, 0);
    acc[1][0] = __builtin_amdgcn_mfma_f32_16x16x32_bf16(af1, bf0, acc[1][0], 0, 0, 0);
    acc[1][1] = __builtin_amdgcn_mfma_f32_16x16x32_bf16(af1, bf1, acc[1][1], 0, 0, 0);
    cur ^= 1;
  }

#pragma unroll
  for (int i = 0; i < 2; ++i) {
    const int grow = rowBase + rw + 16 * i + quad * 4;
#pragma unroll
    for (int j = 0; j < 2; ++j) {
      const int gcol = colBase + cw + 16 * j + l15;
#pragma unroll
      for (int r = 0; r < 4; ++r) {
        float vo = acc[i][j][r];
        if (EPI == 1) vo += (gcol < NV) ? bias[gcol] : 0.f;
        if (EPI == 2) vo = tanhf(vo);
        if (OUT16) C16[(size_t)(grow + r) * ldc + gcol] = f2bf(vo);
        else       C[(size_t)(grow + r) * ldc + gcol] = vo;
      }
    }
  }
}

template<int A16, int EPI, int OUT16>
__global__ __launch_bounds__(256) void gemm_k(
    const float* __restrict__ Af, const unsigned short* __restrict__ Ah,
    const unsigned short* __restrict__ Bt, const float* __restrict__ bias,
    float* __restrict__ C, unsigned short* __restrict__ C16,
    int K, int lda, int ldc)
{
  __shared__ unsigned short As[2 * 64 * 40];
  __shared__ unsigned short Bs[2 * 64 * 40];
  gemm_body<A16, EPI, OUT16>(Af, Ah, Bt, bias, C, C16, K, lda, ldc,
                             blockIdx.x, blockIdx.y, As, Bs);
}

// ---------------------------------------------------------------------------
// Gi precompute: all 21 steps of emb[dec_t] @ W_ih^T, bf16 out. 2D grid.
// ---------------------------------------------------------------------------
__global__ __launch_bounds__(256) void gemm_gather(
    const float* __restrict__ emb, const unsigned short* __restrict__ Wiht,
    unsigned short* __restrict__ Gi, const int* __restrict__ label)
{
  __shared__ unsigned short As[64 * 40];
  __shared__ unsigned short Bs[64 * 40];
  const int tid = threadIdx.x;
  const int rowBase = blockIdx.y * 64, colBase = blockIdx.x * 64;
  const int wave = tid >> 6, lane = tid & 63, quad = lane >> 4, l15 = lane & 15;
  const int rw = (wave & 1) * 32, cw = (wave >> 1) * 32;
  const int K = 256;

  f32x4 acc[2][2];
#pragma unroll
  for (int i = 0; i < 2; ++i)
#pragma unroll
    for (int j = 0; j < 2; ++j)
#pragma unroll
      for (int r = 0; r < 4; ++r) acc[i][j][r] = 0.f;

  const int ar = tid >> 2;
  const int kq = (tid & 3) * 8;
  const int aRowG = rowBase + ar;
  const int t = aRowG >> 9;
  const int b = aRowG & 511;
  const int dec = (t == 0) ? SOS : label[b * LSTR + (t - 1)];
  const float* aptr = emb + (size_t)dec * NE + kq;
  const unsigned short* bptr = Wiht + (size_t)(colBase + ar) * K + kq;
  unsigned short* asd = &As[ar * 40 + kq];
  unsigned short* bsd = &Bs[ar * 40 + kq];

  float4 x0 = *(const float4*)aptr;
  float4 x1 = *(const float4*)(aptr + 4);
  uint4 bv = *(const uint4*)bptr;

  for (int k0 = 0; k0 < K; k0 += 32) {
    uint4 aw;
    aw.x = (unsigned)f2bf(x0.x) | ((unsigned)f2bf(x0.y) << 16);
    aw.y = (unsigned)f2bf(x0.z) | ((unsigned)f2bf(x0.w) << 16);
    aw.z = (unsigned)f2bf(x1.x) | ((unsigned)f2bf(x1.y) << 16);
    aw.w = (unsigned)f2bf(x1.z) | ((unsigned)f2bf(x1.w) << 16);
    *(uint4*)asd = aw;
    *(uint4*)bsd = bv;
    __syncthreads();
    const int kn = k0 + 32;
    if (kn < K) {
      x0 = *(const float4*)(aptr + kn);
      x1 = *(const float4*)(aptr + kn + 4);
      bv = *(const uint4*)(bptr + kn);
    }
    const bf16x8 af0 = *(const bf16x8*)&As[(rw + l15) * 40 + quad * 8];
    const bf16x8 af1 = *(const bf16x8*)&As[(rw + 16 + l15) * 40 + quad * 8];
    const bf16x8 bf0 = *(const bf16x8*)&Bs[(cw + l15) * 40 + quad * 8];
    const bf16x8 bf1 = *(const bf16x8*)&Bs[(cw + 16 + l15) * 40 + quad * 8];
    acc[0][0] = __builtin_amdgcn_mfma_f32_16x16x32_bf16(af0, bf0, acc[0][0], 0, 0, 0);
    acc[0][1] = __builtin_amdgcn_mfma_f32_16x16x32_bf16(af0, bf1, acc[0][1], 0, 0, 0);
    acc[1][0] = __builtin_amdgcn_mfma_f32_16x16x32_bf16(af1, bf0, acc[1][0], 0, 0, 0);
    acc[1][1] = __builtin_amdgcn_mfma_f32_16x16x32_bf16(af1, bf1, acc[1][1], 0, 0, 0);
    __syncthreads();
  }

#pragma unroll
  for (int i = 0; i < 2; ++i) {
    const int grow = rowBase + rw + 16 * i + quad * 4;
#pragma unroll
    for (int j = 0; j < 2; ++j) {
      const int gcol = colBase + cw + 16 * j + l15;
#pragma unroll
      for (int r = 0; r < 4; ++r)
        Gi[(size_t)(grow + r) * 1536 + gcol] = f2bf(acc[i][j][r]);
    }
  }
}

// ---------------------------------------------------------------------------
// Fused recurrent step: h_t @ [r|z|n|u]-packed weights (N'=2048) with GRU
// epilogue.  Grid (8 col-groups, 16 row-tiles of 32).  Block M=32, N=256.
// Wave w owns gate w (cols w*64..w*64+63).  Gates r,z,n exchanged via LDS
// overlay; u written straight to U_all.  notLast==0: only U is produced.
// ---------------------------------------------------------------------------
__global__ __launch_bounds__(256) void step_fused(
    const float* __restrict__ Ht, const unsigned short* __restrict__ W1p,
    const unsigned short* __restrict__ Gi_t,
    const float* __restrict__ b_ih, const float* __restrict__ b_hh,
    float* __restrict__ Hnext, float* __restrict__ Ut, int notLast)
{
  __shared__ __align__(16) char smem[46080];
  unsigned short* As = (unsigned short*)smem;            // 2 x 32 x 40
  unsigned short* Bs = (unsigned short*)(smem + 5120);   // 2 x 256 x 40
  float* Gbuf = (float*)smem;                            // overlay [3][32][72]

  const int tid = threadIdx.x;
  const int wave = tid >> 6, lane = tid & 63, quad = lane >> 4, l15 = lane & 15;
  const int rowBase = blockIdx.y * 32;
  const int colBase = blockIdx.x * 256;

  f32x4 acc[2][4];
#pragma unroll
  for (int i = 0; i < 2; ++i)
#pragma unroll
    for (int j = 0; j < 4; ++j)
#pragma unroll
      for (int r = 0; r < 4; ++r) acc[i][j][r] = 0.f;

  const int ar = tid >> 3;              // A row 0..31
  const int kqa = (tid & 7) * 4;        // 4 k's
  const float* aptr = Ht + (size_t)(rowBase + ar) * NH + kqa;
  const unsigned short* bptr = W1p + (size_t)(colBase + tid) * NH;
  unsigned short* asd = As + ar * 40 + kqa;
  unsigned short* bsd = Bs + tid * 40;

  float4 xa = *(const float4*)aptr;
  uint4 bv0 = *(const uint4*)(bptr + 0);
  uint4 bv1 = *(const uint4*)(bptr + 8);
  uint4 bv2 = *(const uint4*)(bptr + 16);
  uint4 bv3 = *(const uint4*)(bptr + 24);

  int cur = 0;
  for (int k0 = 0; k0 < NH; k0 += 32) {
    ushort4 aw;
    aw.x = f2bf(xa.x); aw.y = f2bf(xa.y); aw.z = f2bf(xa.z); aw.w = f2bf(xa.w);
    *(ushort4*)(asd + cur * 1280) = aw;
    *(uint4*)(bsd + cur * 10240 + 0)  = bv0;
    *(uint4*)(bsd + cur * 10240 + 8)  = bv1;
    *(uint4*)(bsd + cur * 10240 + 16) = bv2;
    *(uint4*)(bsd + cur * 10240 + 24) = bv3;

    const int kn = k0 + 32;
    if (kn < NH) {
      xa = *(const float4*)(aptr + kn);
      bv0 = *(const uint4*)(bptr + kn + 0);
      bv1 = *(const uint4*)(bptr + kn + 8);
      bv2 = *(const uint4*)(bptr + kn + 16);
      bv3 = *(const uint4*)(bptr + kn + 24);
    }
    __syncthreads();

    const unsigned short* Ab = As + cur * 1280;
    const unsigned short* Bb = Bs + cur * 10240;
    const bf16x8 af0 = *(const bf16x8*)&Ab[(l15) * 40 + quad * 8];
    const bf16x8 af1 = *(const bf16x8*)&Ab[(16 + l15) * 40 + quad * 8];
#pragma unroll
    for (int j = 0; j < 4; ++j) {
      const bf16x8 bf = *(const bf16x8*)&Bb[(wave * 64 + j * 16 + l15) * 40 + quad * 8];
      acc[0][j] = __builtin_amdgcn_mfma_f32_16x16x32_bf16(af0, bf, acc[0][j], 0, 0, 0);
      acc[1][j] = __builtin_amdgcn_mfma_f32_16x16x32_bf16(af1, bf, acc[1][j], 0, 0, 0);
    }
    cur ^= 1;
  }
  __syncthreads();   // all LDS reads done before overlay writes

  // write gates: waves 0..2 -> Gbuf, wave 3 -> U_all
#pragma unroll
  for (int i = 0; i < 2; ++i) {
#pragma unroll
    for (int j = 0; j < 4; ++j) {
#pragma unroll
      for (int r = 0; r < 4; ++r) {
        const int rl = 16 * i + quad * 4 + r;
        const int col = j * 16 + l15;
        if (wave == 3)
          Ut[(size_t)(rowBase + rl) * NH + blockIdx.x * 64 + col] = acc[i][j][r];
        else
          Gbuf[(wave * 32 + rl) * 72 + col] = acc[i][j][r];
      }
    }
  }
  __syncthreads();

  if (notLast) {
    const int rl = tid >> 3, c8 = (tid & 7) * 8;
    const int bg = rowBase + rl;
    const int jg = blockIdx.x * 64 + c8;
    const float* g0 = Gbuf + (0 * 32 + rl) * 72 + c8;
    const float* g1 = Gbuf + (1 * 32 + rl) * 72 + c8;
    const float* g2 = Gbuf + (2 * 32 + rl) * 72 + c8;
    const unsigned short* gp = Gi_t + (size_t)bg * 1536;
    float gr[8], gz[8], gn[8];
    { uint4 a = *(const uint4*)(gp + jg);        unp8(a, gr); }
    { uint4 a = *(const uint4*)(gp + 512 + jg);  unp8(a, gz); }
    { uint4 a = *(const uint4*)(gp + 1024 + jg); unp8(a, gn); }
    const float* hR = Ht + (size_t)bg * NH + jg;
    float* hW = Hnext + (size_t)bg * NH + jg;
    const float4 ho0 = *(const float4*)hR;
    const float4 ho1 = *(const float4*)(hR + 4);
    const float hov[8] = {ho0.x, ho0.y, ho0.z, ho0.w, ho1.x, ho1.y, ho1.z, ho1.w};
    float o[8];
#pragma unroll
    for (int c = 0; c < 8; ++c) {
      const int j = jg + c;
      const float ir  = gr[c] + b_ih[j];
      const float iz  = gz[c] + b_ih[512 + j];
      const float inn = gn[c] + b_ih[1024 + j];
      const float hr  = g0[c] + b_hh[j];
      const float hz  = g1[c] + b_hh[512 + j];
      const float hn  = g2[c] + b_hh[1024 + j];
      const float rg = 1.f / (1.f + expf(-(ir + hr)));
      const float zg = 1.f / (1.f + expf(-(iz + hz)));
      const float ng = tanhf(inn + rg * hn);
      o[c] = (1.f - zg) * ng + zg * hov[c];
    }
    *(float4*)hW = make_float4(o[0], o[1], o[2], o[3]);
    *(float4*)(hW + 4) = make_float4(o[4], o[5], o[6], o[7]);
  }
}

// ---------------------------------------------------------------------------
// MFMA day attention.  One block per b.  Q (21 t-rows of U) in registers,
// reused across the 7 days.  Per d: stage E (20x512 f32 -> bf16 LDS, two
// layouts), QK^T (MFMA), parallel masked softmax(20), PV (MFMA), write week.
// ---------------------------------------------------------------------------
__global__ __launch_bounds__(256) void day_attn_mfma(
    const float* __restrict__ enc, const int* __restrict__ numpairs,
    const float* __restrict__ U, unsigned short* __restrict__ week)
{
  __shared__ unsigned short Es[16 * 32 * 40];   // [kchunk][s(32,pad0)][40]
  __shared__ unsigned short ETs[512 * 40];      // [h][s(32,pad0) in 40]
  __shared__ float S_lds[32 * 33];
  __shared__ unsigned short P_lds[32 * 40];

  const int tid = threadIdx.x;
  const int wave = tid >> 6, lane = tid & 63;
  const int quad = lane >> 4, l15 = lane & 15;
  const int b = blockIdx.x;
  const int mt = wave >> 1, nt = wave & 1;

  // zero LDS pads once (Es rows>=20, ETs cols>=20, P cols>=20)
  {
    unsigned* p1 = (unsigned*)Es;
    for (int i = tid; i < 10240; i += 256) p1[i] = 0;
    unsigned* p2 = (unsigned*)ETs;
    for (int i = tid; i < 10240; i += 256) p2[i] = 0;
    unsigned* p3 = (unsigned*)P_lds;
    for (int i = tid; i < 640; i += 256) p3[i] = 0;
  }

  // Q fragments in registers: row m = mt*16+l15 -> t (clamped), 16 k-steps
  bf16x8 qa[16];
  {
    const int m = mt * 16 + l15;
    const int t = (m < NT + 1) ? m : NT;
    const float* qp = U + ((size_t)t * NB + b) * NH + quad * 8;
#pragma unroll
    for (int ks = 0; ks < 16; ++ks) {
      const float4 lo = *(const float4*)(qp + ks * 32);
      const float4 hi = *(const float4*)(qp + ks * 32 + 4);
      union { bf16x8 v; ushort u[8]; } pk;
      pk.u[0] = f2bf(lo.x); pk.u[1] = f2bf(lo.y); pk.u[2] = f2bf(lo.z); pk.u[3] = f2bf(lo.w);
      pk.u[4] = f2bf(hi.x); pk.u[5] = f2bf(hi.y); pk.u[6] = f2bf(hi.z); pk.u[7] = f2bf(hi.w);
      qa[ks] = pk.v;
    }
  }
  __syncthreads();

  for (int d = 0; d < ND; ++d) {
    // ---- stage E_d into both layouts ----
    const float* eb = enc + ((size_t)b * NS + d * DL) * NH;
    for (int f = tid; f < DL * NH / 4; f += 256) {
      const int s = f >> 7, c4 = f & 127, h = c4 * 4;
      const float4 v = *(const float4*)(eb + s * NH + h);
      const unsigned short h0 = f2bf(v.x), h1 = f2bf(v.y),
                           h2 = f2bf(v.z), h3 = f2bf(v.w);
      ushort4 hs; hs.x = h0; hs.y = h1; hs.z = h2; hs.w = h3;
      *(ushort4*)&Es[((h >> 5) * 32 + s) * 40 + (h & 31)] = hs;
      ETs[(h + 0) * 40 + s] = h0;
      ETs[(h + 1) * 40 + s] = h1;
      ETs[(h + 2) * 40 + s] = h2;
      ETs[(h + 3) * 40 + s] = h3;
    }
    __syncthreads();

    // ---- QK^T : wave (mt,nt) computes 16x16 S tile ----
    f32x4 sacc = {0.f, 0.f, 0.f, 0.f};
#pragma unroll
    for (int ks = 0; ks < 16; ++ks) {
      const bf16x8 bf = *(const bf16x8*)&Es[(ks * 32 + nt * 16 + l15) * 40 + quad * 8];
      sacc = __builtin_amdgcn_mfma_f32_16x16x32_bf16(qa[ks], bf, sacc, 0, 0, 0);
    }
#pragma unroll
    for (int r = 0; r < 4; ++r)
      S_lds[(mt * 16 + quad * 4 + r) * 33 + nt * 16 + l15] = sacc[r];
    __syncthreads();

    // ---- masked softmax over s (8 threads per row) ----
    {
      const int r = tid >> 3, c = tid & 7;
      const int base = b * NS + d * DL;
      float v0 = S_lds[r * 33 + c];
      if (numpairs[base + c] == 0) v0 = -1e9f;
      float v1 = S_lds[r * 33 + c + 8];
      if (numpairs[base + c + 8] == 0) v1 = -1e9f;
      float v2 = -1e30f;
      if (c < 4) {
        v2 = S_lds[r * 33 + c + 16];
        if (numpairs[base + c + 16] == 0) v2 = -1e9f;
      }
      float mx = fmaxf(fmaxf(v0, v1), v2);
      mx = fmaxf(mx, __shfl_xor(mx, 1));
      mx = fmaxf(mx, __shfl_xor(mx, 2));
      mx = fmaxf(mx, __shfl_xor(mx, 4));
      const float e0 = expf(v0 - mx), e1 = expf(v1 - mx);
      const float e2 = (c < 4) ? expf(v2 - mx) : 0.f;
      float sm = e0 + e1 + e2;
      sm += __shfl_xor(sm, 1);
      sm += __shfl_xor(sm, 2);
      sm += __shfl_xor(sm, 4);
      const float inv = 1.f / sm;
      P_lds[r * 40 + c] = f2bf(e0 * inv);
      P_lds[r * 40 + c + 8] = f2bf(e1 * inv);
      if (c < 4) P_lds[r * 40 + c + 16] = f2bf(e2 * inv);
    }
    __syncthreads();

    // ---- PV : wave (mt,nt) covers rows mt*16, h-cols nt*256 .. +255 ----
    const bf16x8 pa = *(const bf16x8*)&P_lds[(mt * 16 + l15) * 40 + quad * 8];
#pragma unroll
    for (int j = 0; j < 16; ++j) {
      const int hcol = nt * 256 + j * 16;
      const bf16x8 bf = *(const bf16x8*)&ETs[(hcol + l15) * 40 + quad * 8];
      f32x4 oacc = {0.f, 0.f, 0.f, 0.f};
      oacc = __builtin_amdgcn_mfma_f32_16x16x32_bf16(pa, bf, oacc, 0, 0, 0);
#pragma unroll
      for (int r = 0; r < 4; ++r) {
        const int t = mt * 16 + quad * 4 + r;
        if (t < NT)
          week[(((size_t)t * NB + b) * ND + d) * NH + hcol + l15] = f2bf(oacc[r]);
      }
    }
    __syncthreads();
  }
}

// ---------------------------------------------------------------------------
// Batched week attention + ctx + concat.  One block = (t, 16 b's).
// ---------------------------------------------------------------------------
__global__ __launch_bounds__(256) void wk_ctx(
    const float* __restrict__ U, const unsigned short* __restrict__ week,
    const float* __restrict__ H, unsigned short* __restrict__ concat)
{
  __shared__ float scS[16 * ND];
  __shared__ float awS[16 * ND];
  const int tid = threadIdx.x;
  const int t = blockIdx.x >> 5;
  const int grp = blockIdx.x & 31;
  const int b16 = tid >> 4, k16 = tid & 15;
  const int b = grp * 16 + b16;
  const float* vp = U + ((size_t)(t + 1) * NB + b) * NH + k16 * 32;
  const size_t wrow = ((size_t)t * NB + b) * ND;

  for (int d = 0; d < ND; ++d) {
    const unsigned short* wp = week + (wrow + d) * NH + k16 * 32;
    float p = 0.f;
#pragma unroll
    for (int q = 0; q < 8; ++q) {
      const float4 a = *(const float4*)(vp + q * 4);
      const ushort4 wv = *(const ushort4*)(wp + q * 4);
      p += a.x * bf2f(wv.x) + a.y * bf2f(wv.y) + a.z * bf2f(wv.z) + a.w * bf2f(wv.w);
    }
    p += __shfl_down(p, 8); p += __shfl_down(p, 4);
    p += __shfl_down(p, 2); p += __shfl_down(p, 1);
    if (k16 == 0) scS[b16 * ND + d] = p;
  }
  __syncthreads();
  if (tid < 16) {
    float s[ND], mx = -1e30f;
    for (int d = 0; d < ND; ++d) { s[d] = scS[tid * ND + d]; mx = fmaxf(mx, s[d]); }
    float sum = 0.f;
    for (int d = 0; d < ND; ++d) { float e = expf(s[d] - mx); s[d] = e; sum += e; }
    const float inv = 1.f / sum;
    for (int d = 0; d < ND; ++d) awS[tid * ND + d] = s[d] * inv;
  }
  __syncthreads();

  const int c0 = k16 * 32;
  const float* hp = H + ((size_t)(t + 1) * NB + b) * NH + c0;
  float aw[ND];
#pragma unroll
  for (int d = 0; d < ND; ++d) aw[d] = awS[b16 * ND + d];
  unsigned short* crow = concat + ((size_t)t * NB + b) * 1024;
#pragma unroll
  for (int q = 0; q < 8; ++q) {
    const int c = c0 + q * 4;
    const float4 hv = *(const float4*)(hp + q * 4);
    ushort4 hs;
    hs.x = f2bf(hv.x); hs.y = f2bf(hv.y); hs.z = f2bf(hv.z); hs.w = f2bf(hv.w);
    *(ushort4*)(crow + c) = hs;
    float4 cv = make_float4(0.f, 0.f, 0.f, 0.f);
#pragma unroll
    for (int d = 0; d < ND; ++d) {
      const ushort4 wv = *(const ushort4*)(week + (wrow + d) * NH + c);
      cv.x += aw[d] * bf2f(wv.x); cv.y += aw[d] * bf2f(wv.y);
      cv.z += aw[d] * bf2f(wv.z); cv.w += aw[d] * bf2f(wv.w);
    }
    ushort4 cs;
    cs.x = f2bf(cv.x); cs.y = f2bf(cv.y); cs.z = f2bf(cv.z); cs.w = f2bf(cv.w);
    *(ushort4*)(crow + 512 + c) = cs;
  }
}

// ---------------------------------------------------------------------------
// Single-pass log_softmax, row in registers.  Row r = t*NB+b -> out[b,t,:].
// ---------------------------------------------------------------------------
__global__ __launch_bounds__(256) void lsm_k(
    const float* __restrict__ logits, float* __restrict__ out)
{
  __shared__ float red[8];
  const int tid = threadIdx.x;
  const int wave = tid >> 6, lane = tid & 63;
  const int r = blockIdx.x;
  const int t = r >> 9, b = r & (NB - 1);
  const float* row = logits + (size_t)r * NVP;
  float v[4];
  float mx = -1e30f;
#pragma unroll
  for (int k = 0; k < 4; ++k) {
    const int c = tid + k * 256;
    v[k] = row[c];
    if (c < NV) mx = fmaxf(mx, v[k]);
  }
#pragma unroll
  for (int off = 32; off; off >>= 1) mx = fmaxf(mx, __shfl_xor(mx, off));
  if (lane == 0) red[wave] = mx;
  __syncthreads();
  mx = fmaxf(fmaxf(red[0], red[1]), fmaxf(red[2], red[3]));
  float s = 0.f;
#pragma unroll
  for (int k = 0; k < 4; ++k) {
    const int c = tid + k * 256;
    if (c < NV) s += expf(v[k] - mx);
  }
#pragma unroll
  for (int off = 32; off; off >>= 1) s += __shfl_xor(s, off);
  if (lane == 0) red[4 + wave] = s;
  __syncthreads();
  const float lse = mx + logf(red[4] + red[5] + red[6] + red[7]);
  float* orow = out + ((size_t)b * NT + t) * NV;
#pragma unroll
  for (int k = 0; k < 4; ++k) {
    const int c = tid + k * 256;
    if (c < NV) orow[c] = v[k] - lse;
  }
}

__global__ void write_last(const int* __restrict__ label, float* __restrict__ out2)
{
  const int b = blockIdx.x * 256 + threadIdx.x;
  if (b < NB) out2[b] = (float)label[b * LSTR + (NT - 1)];
}

// W1p[n'][k]: n' = g*256 + gate*64 + (j - g*64), gate 0..2 = W_hh rows, 3 = Wa^T
__global__ __launch_bounds__(256) void pack_w1p(
    const float* __restrict__ Whh, const float* __restrict__ Wa,
    unsigned short* __restrict__ W1p)
{
  const int idx = blockIdx.x * 256 + threadIdx.x;
  const int np = idx >> 9, k = idx & 511;
  const int g = np >> 8, rem = np & 255, gate = rem >> 6, j = g * 64 + (rem & 63);
  float v;
  if (gate < 3) v = Whh[(size_t)(gate * 512 + j) * 512 + k];
  else          v = Wa[(size_t)k * 512 + j];
  W1p[idx] = f2bf(v);
}

__global__ __launch_bounds__(256) void cast4(
    const float4* __restrict__ in, ushort4* __restrict__ out, int n4)
{
  const int i = blockIdx.x * 256 + threadIdx.x;
  if (i < n4) {
    const float4 x = in[i];
    ushort4 r;
    r.x = f2bf(x.x); r.y = f2bf(x.y); r.z = f2bf(x.z); r.w = f2bf(x.w);
    out[i] = r;
  }
}

extern "C" void kernel_launch(void* const* d_in, const int* in_sizes, int n_in,
                              void* d_out, int out_size, void* d_ws, size_t ws_size,
                              hipStream_t stream)
{
  const float* enc_h  = (const float*)d_in[0];
  const float* enc    = (const float*)d_in[1];
  const int*   label  = (const int*)d_in[2];
  const int*   numprs = (const int*)d_in[3];
  const float* emb    = (const float*)d_in[4];
  const float* W_ih   = (const float*)d_in[5];
  const float* W_hh   = (const float*)d_in[6];
  const float* b_ih   = (const float*)d_in[7];
  const float* b_hh   = (const float*)d_in[8];
  const float* Wa     = (const float*)d_in[9];
  const float* wa_W   = (const float*)d_in[10];
  const float* fc_W   = (const float*)d_in[11];
  const float* fc_b   = (const float*)d_in[12];
  float* out = (float*)d_out;

  float* f = (float*)d_ws;
  float* H_all   = f; f += (size_t)(NT + 1) * NB * NH;   // 22 hidden states
  float* U_all   = f; f += (size_t)(NT + 1) * NB * NH;   // h_t @ Wa, all t
  float* logitsW = f; f += (size_t)NROW * NVP;
  unsigned short* us = (unsigned short*)f;
  unsigned short* W1p    = us; us += (size_t)2048 * 512;
  unsigned short* W3t    = us; us += (size_t)512 * 1024;
  unsigned short* W4t    = us; us += (size_t)NVP * 512;
  unsigned short* Wiht   = us; us += (size_t)1536 * 256;
  unsigned short* Gi     = us; us += (size_t)NT * NB * 1536;
  unsigned short* week   = us; us += (size_t)NT * NB * ND * NH;
  unsigned short* concatW= us; us += (size_t)NROW * 1024;
  unsigned short* aBuf   = us; us += (size_t)NROW * 512;

  const dim3 blk(256);
  const size_t BH = (size_t)NB * NH;

  hipMemcpyAsync(H_all, enc_h, BH * sizeof(float),
                 hipMemcpyDeviceToDevice, stream);

  // --- setup: weight packs/casts + Gi precompute ---
  pack_w1p<<<dim3(2048 * 512 / 256), blk, 0, stream>>>(W_hh, Wa, W1p);
  cast4<<<dim3(512 * 1024 / 4 / 256), blk, 0, stream>>>(
      (const float4*)wa_W, (ushort4*)W3t, 512 * 1024 / 4);
  cast4<<<dim3((NV * 512 / 4 + 255) / 256), blk, 0, stream>>>(
      (const float4*)fc_W, (ushort4*)W4t, NV * 512 / 4);
  hipMemsetAsync(W4t + (size_t)NV * 512, 0, (size_t)(NVP - NV) * 512 * 2, stream);
  cast4<<<dim3(1536 * 256 / 4 / 256), blk, 0, stream>>>(
      (const float4*)W_ih, (ushort4*)Wiht, 1536 * 256 / 4);
  gemm_gather<<<dim3(24, NT * 8), blk, 0, stream>>>(emb, Wiht, Gi, label);

  // --- recurrent phase: fused GEMM+GRU, one kernel per step ---
  // t = NT runs u-only (produces U_all[21] for week attention).
  for (int t = 0; t <= NT; ++t) {
    const int notLast = (t < NT) ? 1 : 0;
    const int tg = (t < NT) ? t : NT - 1;   // Gi index (unused when last)
    step_fused<<<dim3(8, 16), blk, 0, stream>>>(
        H_all + (size_t)t * BH, W1p, Gi + (size_t)tg * NB * 1536,
        b_ih, b_hh,
        H_all + (size_t)(notLast ? t + 1 : t) * BH,
        U_all + (size_t)t * BH, notLast);
  }

  // --- batched tail ---
  day_attn_mfma<<<dim3(NB), blk, 0, stream>>>(enc, numprs, U_all, week);
  wk_ctx<<<dim3(NT * 32), blk, 0, stream>>>(U_all, week, H_all, concatW);
  gemm_k<1, 2, 1><<<dim3(8, NROW / 64), blk, 0, stream>>>(
      nullptr, concatW, W3t, nullptr, nullptr, aBuf, 1024, 1024, 512);
  gemm_k<1, 1, 0><<<dim3(16, NROW / 64), blk, 0, stream>>>(
      nullptr, aBuf, W4t, fc_b, logitsW, nullptr, 512, 512, NVP);
  lsm_k<<<dim3(NROW), blk, 0, stream>>>(logitsW, out);
  write_last<<<dim3(2), blk, 0, stream>>>(label, out + (size_t)NB * NT * NV);
}

// Round 3
// 792.067 us; speedup vs baseline: 1.8834x; 1.1542x over previous
//
#include <hip/hip_runtime.h>
#include <math.h>

typedef __attribute__((ext_vector_type(8))) short bf16x8;
typedef __attribute__((ext_vector_type(4))) float f32x4;

constexpr int NB = 512;
constexpr int NS = 140;
constexpr int NH = 512;
constexpr int NE = 256;
constexpr int NV = 1000;
constexpr int NVP = 1024;   // padded vocab
constexpr int NT = 21;
constexpr int ND = 7;
constexpr int DL = 20;
constexpr int SOS = 2;
constexpr int LSTR = NT + 1;
constexpr int NROW = NT * NB;       // 10752 batched (t,b) rows

__device__ __forceinline__ unsigned short f2bf(float f) {
  union { float f; unsigned u; } v; v.f = f;
  unsigned r = v.u + 0x7fffu + ((v.u >> 16) & 1u);
  return (unsigned short)(r >> 16);
}
__device__ __forceinline__ float bf2f(unsigned short h) {
  union { unsigned u; float f; } v; v.u = ((unsigned)h) << 16;
  return v.f;
}
__device__ __forceinline__ void unp8(uint4 v, float* o) {
  o[0] = bf2f((unsigned short)(v.x & 0xffffu)); o[1] = bf2f((unsigned short)(v.x >> 16));
  o[2] = bf2f((unsigned short)(v.y & 0xffffu)); o[3] = bf2f((unsigned short)(v.y >> 16));
  o[4] = bf2f((unsigned short)(v.z & 0xffffu)); o[5] = bf2f((unsigned short)(v.z >> 16));
  o[6] = bf2f((unsigned short)(v.w & 0xffffu)); o[7] = bf2f((unsigned short)(v.w >> 16));
}

// ---------------------------------------------------------------------------
// 64x64 MFMA tile body, double-buffered LDS (ONE barrier per K-chunk).
// A16: bf16 A. EPI: 0 none, 1 +bias (guarded col<NV), 2 tanh. OUT16: bf16 out.
// ---------------------------------------------------------------------------
template<int A16, int EPI, int OUT16>
__device__ __forceinline__ void gemm_body(
    const float* __restrict__ Af, const unsigned short* __restrict__ Ah,
    const unsigned short* __restrict__ Bt, const float* __restrict__ bias,
    float* __restrict__ C, unsigned short* __restrict__ C16,
    int K, int lda, int ldc, int bx, int by,
    unsigned short* As, unsigned short* Bs)
{
  const int tid = threadIdx.x;
  const int rowBase = by * 64, colBase = bx * 64;
  const int wave = tid >> 6, lane = tid & 63, quad = lane >> 4, l15 = lane & 15;
  const int rw = (wave & 1) * 32, cw = (wave >> 1) * 32;

  f32x4 acc[2][2];
#pragma unroll
  for (int i = 0; i < 2; ++i)
#pragma unroll
    for (int j = 0; j < 2; ++j)
#pragma unroll
      for (int r = 0; r < 4; ++r) acc[i][j][r] = 0.f;

  const int ar = tid >> 2;
  const int kq = (tid & 3) * 8;
  const float* aptrf = nullptr;
  const unsigned short* aptrh = nullptr;
  if (A16) aptrh = Ah + (size_t)(rowBase + ar) * lda + kq;
  else     aptrf = Af + (size_t)(rowBase + ar) * lda + kq;
  const unsigned short* bptr = Bt + (size_t)(colBase + ar) * K + kq;
  unsigned short* asd = &As[ar * 40 + kq];
  unsigned short* bsd = &Bs[ar * 40 + kq];

  float4 x0, x1;
  uint4 av;
  if (A16) {
    av = *(const uint4*)aptrh;
  } else {
    x0 = *(const float4*)aptrf; x1 = *(const float4*)(aptrf + 4);
  }
  uint4 bv = *(const uint4*)bptr;

  int cur = 0;
  for (int k0 = 0; k0 < K; k0 += 32) {
    uint4 aw;
    if (A16) {
      aw = av;
    } else {
      aw.x = (unsigned)f2bf(x0.x) | ((unsigned)f2bf(x0.y) << 16);
      aw.y = (unsigned)f2bf(x0.z) | ((unsigned)f2bf(x0.w) << 16);
      aw.z = (unsigned)f2bf(x1.x) | ((unsigned)f2bf(x1.y) << 16);
      aw.w = (unsigned)f2bf(x1.z) | ((unsigned)f2bf(x1.w) << 16);
    }
    *(uint4*)(asd + cur * 2560) = aw;
    *(uint4*)(bsd + cur * 2560) = bv;

    const int kn = k0 + 32;
    if (kn < K) {
      if (A16) {
        av = *(const uint4*)(aptrh + kn);
      } else {
        x0 = *(const float4*)(aptrf + kn);
        x1 = *(const float4*)(aptrf + kn + 4);
      }
      bv = *(const uint4*)(bptr + kn);
    }
    __syncthreads();

    const unsigned short* Ab = As + cur * 2560;
    const unsigned short* Bb = Bs + cur * 2560;
    const bf16x8 af0 = *(const bf16x8*)&Ab[(rw + l15) * 40 + quad * 8];
    const bf16x8 af1 = *(const bf16x8*)&Ab[(rw + 16 + l15) * 40 + quad * 8];
    const bf16x8 bf0 = *(const bf16x8*)&Bb[(cw + l15) * 40 + quad * 8];
    const bf16x8 bf1 = *(const bf16x8*)&Bb[(cw + 16 + l15) * 40 + quad * 8];
    acc[0][0] = __builtin_amdgcn_mfma_f32_16x16x32_bf16(af0, bf0, acc[0][0], 0, 0, 0);
    acc[0][1] = __builtin_amdgcn_mfma_f32_16x16x32_bf16(af0, bf1, acc[0][1], 0, 0, 0);
    acc[1][0] = __builtin_amdgcn_mfma_f32_16x16x32_bf16(af1, bf0, acc[1][0], 0, 0, 0);
    acc[1][1] = __builtin_amdgcn_mfma_f32_16x16x32_bf16(af1, bf1, acc[1][1], 0, 0, 0);
    cur ^= 1;
  }

#pragma unroll
  for (int i = 0; i < 2; ++i) {
    const int grow = rowBase + rw + 16 * i + quad * 4;
#pragma unroll
    for (int j = 0; j < 2; ++j) {
      const int gcol = colBase + cw + 16 * j + l15;
#pragma unroll
      for (int r = 0; r < 4; ++r) {
        float vo = acc[i][j][r];
        if (EPI == 1) vo += (gcol < NV) ? bias[gcol] : 0.f;
        if (EPI == 2) vo = tanhf(vo);
        if (OUT16) C16[(size_t)(grow + r) * ldc + gcol] = f2bf(vo);
        else       C[(size_t)(grow + r) * ldc + gcol] = vo;
      }
    }
  }
}

template<int A16, int EPI, int OUT16>
__global__ __launch_bounds__(256) void gemm_k(
    const float* __restrict__ Af, const unsigned short* __restrict__ Ah,
    const unsigned short* __restrict__ Bt, const float* __restrict__ bias,
    float* __restrict__ C, unsigned short* __restrict__ C16,
    int K, int lda, int ldc)
{
  __shared__ unsigned short As[2 * 64 * 40];
  __shared__ unsigned short Bs[2 * 64 * 40];
  gemm_body<A16, EPI, OUT16>(Af, Ah, Bt, bias, C, C16, K, lda, ldc,
                             blockIdx.x, blockIdx.y, As, Bs);
}

// ---------------------------------------------------------------------------
// Gi precompute: all 21 steps of emb[dec_t] @ W_ih^T, bf16 out. 2D grid.
// ---------------------------------------------------------------------------
__global__ __launch_bounds__(256) void gemm_gather(
    const float* __restrict__ emb, const unsigned short* __restrict__ Wiht,
    unsigned short* __restrict__ Gi, const int* __restrict__ label)
{
  __shared__ unsigned short As[64 * 40];
  __shared__ unsigned short Bs[64 * 40];
  const int tid = threadIdx.x;
  const int rowBase = blockIdx.y * 64, colBase = blockIdx.x * 64;
  const int wave = tid >> 6, lane = tid & 63, quad = lane >> 4, l15 = lane & 15;
  const int rw = (wave & 1) * 32, cw = (wave >> 1) * 32;
  const int K = 256;

  f32x4 acc[2][2];
#pragma unroll
  for (int i = 0; i < 2; ++i)
#pragma unroll
    for (int j = 0; j < 2; ++j)
#pragma unroll
      for (int r = 0; r < 4; ++r) acc[i][j][r] = 0.f;

  const int ar = tid >> 2;
  const int kq = (tid & 3) * 8;
  const int aRowG = rowBase + ar;
  const int t = aRowG >> 9;
  const int b = aRowG & 511;
  const int dec = (t == 0) ? SOS : label[b * LSTR + (t - 1)];
  const float* aptr = emb + (size_t)dec * NE + kq;
  const unsigned short* bptr = Wiht + (size_t)(colBase + ar) * K + kq;
  unsigned short* asd = &As[ar * 40 + kq];
  unsigned short* bsd = &Bs[ar * 40 + kq];

  float4 x0 = *(const float4*)aptr;
  float4 x1 = *(const float4*)(aptr + 4);
  uint4 bv = *(const uint4*)bptr;

  for (int k0 = 0; k0 < K; k0 += 32) {
    uint4 aw;
    aw.x = (unsigned)f2bf(x0.x) | ((unsigned)f2bf(x0.y) << 16);
    aw.y = (unsigned)f2bf(x0.z) | ((unsigned)f2bf(x0.w) << 16);
    aw.z = (unsigned)f2bf(x1.x) | ((unsigned)f2bf(x1.y) << 16);
    aw.w = (unsigned)f2bf(x1.z) | ((unsigned)f2bf(x1.w) << 16);
    *(uint4*)asd = aw;
    *(uint4*)bsd = bv;
    __syncthreads();
    const int kn = k0 + 32;
    if (kn < K) {
      x0 = *(const float4*)(aptr + kn);
      x1 = *(const float4*)(aptr + kn + 4);
      bv = *(const uint4*)(bptr + kn);
    }
    const bf16x8 af0 = *(const bf16x8*)&As[(rw + l15) * 40 + quad * 8];
    const bf16x8 af1 = *(const bf16x8*)&As[(rw + 16 + l15) * 40 + quad * 8];
    const bf16x8 bf0 = *(const bf16x8*)&Bs[(cw + l15) * 40 + quad * 8];
    const bf16x8 bf1 = *(const bf16x8*)&Bs[(cw + 16 + l15) * 40 + quad * 8];
    acc[0][0] = __builtin_amdgcn_mfma_f32_16x16x32_bf16(af0, bf0, acc[0][0], 0, 0, 0);
    acc[0][1] = __builtin_amdgcn_mfma_f32_16x16x32_bf16(af0, bf1, acc[0][1], 0, 0, 0);
    acc[1][0] = __builtin_amdgcn_mfma_f32_16x16x32_bf16(af1, bf0, acc[1][0], 0, 0, 0);
    acc[1][1] = __builtin_amdgcn_mfma_f32_16x16x32_bf16(af1, bf1, acc[1][1], 0, 0, 0);
    __syncthreads();
  }

#pragma unroll
  for (int i = 0; i < 2; ++i) {
    const int grow = rowBase + rw + 16 * i + quad * 4;
#pragma unroll
    for (int j = 0; j < 2; ++j) {
      const int gcol = colBase + cw + 16 * j + l15;
#pragma unroll
      for (int r = 0; r < 4; ++r)
        Gi[(size_t)(grow + r) * 1536 + gcol] = f2bf(acc[i][j][r]);
    }
  }
}

// ---------------------------------------------------------------------------
// Fused recurrent step: h_t @ [r|z|n|u]-packed weights (N'=2048) with GRU
// epilogue.  W1pk is k-chunked: [k/32][n(2048)][32] so staging is a fully
// contiguous 16 KB read per block per chunk.
// ---------------------------------------------------------------------------
__global__ __launch_bounds__(256) void step_fused(
    const float* __restrict__ Ht, const unsigned short* __restrict__ W1pk,
    const unsigned short* __restrict__ Gi_t,
    const float* __restrict__ b_ih, const float* __restrict__ b_hh,
    float* __restrict__ Hnext, float* __restrict__ Ut, int notLast)
{
  __shared__ __align__(16) char smem[46080];
  unsigned short* As = (unsigned short*)smem;            // 2 x 32 x 40
  unsigned short* Bs = (unsigned short*)(smem + 5120);   // 2 x 256 x 40
  float* Gbuf = (float*)smem;                            // overlay [3][32][72]

  const int tid = threadIdx.x;
  const int wave = tid >> 6, lane = tid & 63, quad = lane >> 4, l15 = lane & 15;
  const int rowBase = blockIdx.y * 32;
  const int colBase = blockIdx.x * 256;

  f32x4 acc[2][4];
#pragma unroll
  for (int i = 0; i < 2; ++i)
#pragma unroll
    for (int j = 0; j < 4; ++j)
#pragma unroll
      for (int r = 0; r < 4; ++r) acc[i][j][r] = 0.f;

  const int ar = tid >> 3;              // A row 0..31
  const int kqa = (tid & 7) * 4;        // 4 k's
  const float* aptr = Ht + (size_t)(rowBase + ar) * NH + kqa;
  const unsigned short* bbase = W1pk + (size_t)(colBase + tid) * 32;
  unsigned short* asd = As + ar * 40 + kqa;
  unsigned short* bsd = Bs + tid * 40;

  float4 xa = *(const float4*)aptr;
  uint4 bv0 = *(const uint4*)(bbase + 0);
  uint4 bv1 = *(const uint4*)(bbase + 8);
  uint4 bv2 = *(const uint4*)(bbase + 16);
  uint4 bv3 = *(const uint4*)(bbase + 24);

  int cur = 0;
  for (int k0 = 0; k0 < NH; k0 += 32) {
    ushort4 aw;
    aw.x = f2bf(xa.x); aw.y = f2bf(xa.y); aw.z = f2bf(xa.z); aw.w = f2bf(xa.w);
    *(ushort4*)(asd + cur * 1280) = aw;
    *(uint4*)(bsd + cur * 10240 + 0)  = bv0;
    *(uint4*)(bsd + cur * 10240 + 8)  = bv1;
    *(uint4*)(bsd + cur * 10240 + 16) = bv2;
    *(uint4*)(bsd + cur * 10240 + 24) = bv3;

    const int kn = k0 + 32;
    if (kn < NH) {
      xa = *(const float4*)(aptr + kn);
      const unsigned short* nb = bbase + (size_t)(kn >> 5) * (2048 * 32);
      bv0 = *(const uint4*)(nb + 0);
      bv1 = *(const uint4*)(nb + 8);
      bv2 = *(const uint4*)(nb + 16);
      bv3 = *(const uint4*)(nb + 24);
    }
    __syncthreads();

    const unsigned short* Ab = As + cur * 1280;
    const unsigned short* Bb = Bs + cur * 10240;
    const bf16x8 af0 = *(const bf16x8*)&Ab[(l15) * 40 + quad * 8];
    const bf16x8 af1 = *(const bf16x8*)&Ab[(16 + l15) * 40 + quad * 8];
#pragma unroll
    for (int j = 0; j < 4; ++j) {
      const bf16x8 bf = *(const bf16x8*)&Bb[(wave * 64 + j * 16 + l15) * 40 + quad * 8];
      acc[0][j] = __builtin_amdgcn_mfma_f32_16x16x32_bf16(af0, bf, acc[0][j], 0, 0, 0);
      acc[1][j] = __builtin_amdgcn_mfma_f32_16x16x32_bf16(af1, bf, acc[1][j], 0, 0, 0);
    }
    cur ^= 1;
  }
  __syncthreads();   // all LDS reads done before overlay writes

  // write gates: waves 0..2 -> Gbuf, wave 3 -> U_all
#pragma unroll
  for (int i = 0; i < 2; ++i) {
#pragma unroll
    for (int j = 0; j < 4; ++j) {
#pragma unroll
      for (int r = 0; r < 4; ++r) {
        const int rl = 16 * i + quad * 4 + r;
        const int col = j * 16 + l15;
        if (wave == 3)
          Ut[(size_t)(rowBase + rl) * NH + blockIdx.x * 64 + col] = acc[i][j][r];
        else
          Gbuf[(wave * 32 + rl) * 72 + col] = acc[i][j][r];
      }
    }
  }
  __syncthreads();

  if (notLast) {
    const int rl = tid >> 3, c8 = (tid & 7) * 8;
    const int bg = rowBase + rl;
    const int jg = blockIdx.x * 64 + c8;
    const float* g0 = Gbuf + (0 * 32 + rl) * 72 + c8;
    const float* g1 = Gbuf + (1 * 32 + rl) * 72 + c8;
    const float* g2 = Gbuf + (2 * 32 + rl) * 72 + c8;
    const unsigned short* gp = Gi_t + (size_t)bg * 1536;
    float gr[8], gz[8], gn[8];
    { uint4 a = *(const uint4*)(gp + jg);        unp8(a, gr); }
    { uint4 a = *(const uint4*)(gp + 512 + jg);  unp8(a, gz); }
    { uint4 a = *(const uint4*)(gp + 1024 + jg); unp8(a, gn); }
    const float* hR = Ht + (size_t)bg * NH + jg;
    float* hW = Hnext + (size_t)bg * NH + jg;
    const float4 ho0 = *(const float4*)hR;
    const float4 ho1 = *(const float4*)(hR + 4);
    const float hov[8] = {ho0.x, ho0.y, ho0.z, ho0.w, ho1.x, ho1.y, ho1.z, ho1.w};
    float o[8];
#pragma unroll
    for (int c = 0; c < 8; ++c) {
      const int j = jg + c;
      const float ir  = gr[c] + b_ih[j];
      const float iz  = gz[c] + b_ih[512 + j];
      const float inn = gn[c] + b_ih[1024 + j];
      const float hr  = g0[c] + b_hh[j];
      const float hz  = g1[c] + b_hh[512 + j];
      const float hn  = g2[c] + b_hh[1024 + j];
      const float rg = 1.f / (1.f + expf(-(ir + hr)));
      const float zg = 1.f / (1.f + expf(-(iz + hz)));
      const float ng = tanhf(inn + rg * hn);
      o[c] = (1.f - zg) * ng + zg * hov[c];
    }
    *(float4*)hW = make_float4(o[0], o[1], o[2], o[3]);
    *(float4*)(hW + 4) = make_float4(o[4], o[5], o[6], o[7]);
  }
}

// ---------------------------------------------------------------------------
// MFMA day attention, one block per (b,d).  3584 blocks, ~81 KB LDS ->
// 2 blocks/CU.  Single pass: stage E (row-major bf16 + transposed copy),
// QK^T (MFMA, B read straight from row-major E), masked softmax(20),
// PV (MFMA), write week.  3 barriers per block.
// ---------------------------------------------------------------------------
__global__ __launch_bounds__(256) void day_attn_mfma(
    const float* __restrict__ enc, const int* __restrict__ numpairs,
    const float* __restrict__ U, unsigned short* __restrict__ week)
{
  __shared__ unsigned short Erow[32 * 520];   // [s][h], pad 8 (rows>=20 unused)
  __shared__ unsigned short ETs[512 * 40];    // [h][s], cols>=20 zeroed
  __shared__ float S_lds[32 * 33];
  __shared__ unsigned short P_lds[32 * 40];

  const int tid = threadIdx.x;
  const int wave = tid >> 6, lane = tid & 63;
  const int quad = lane >> 4, l15 = lane & 15;
  const int b = blockIdx.x / ND, d = blockIdx.x % ND;
  const int mt = wave >> 1, nt = wave & 1;

  // zero ETs (pad cols must be 0: P=0 * NaN garbage would poison PV) and P pads
  {
    unsigned* p2 = (unsigned*)ETs;
    for (int i = tid; i < 10240; i += 256) p2[i] = 0;
    unsigned* p3 = (unsigned*)P_lds;
    for (int i = tid; i < 640; i += 256) p3[i] = 0;
  }

  // stage E_d: row-major bf16 + transposed copy
  const float* eb = enc + ((size_t)b * NS + d * DL) * NH;
  for (int f = tid; f < DL * NH / 4; f += 256) {
    const int s = f >> 7, c4 = f & 127, h = c4 * 4;
    const float4 v = *(const float4*)(eb + s * NH + h);
    const unsigned short h0 = f2bf(v.x), h1 = f2bf(v.y),
                         h2 = f2bf(v.z), h3 = f2bf(v.w);
    ushort4 hs; hs.x = h0; hs.y = h1; hs.z = h2; hs.w = h3;
    *(ushort4*)&Erow[s * 520 + h] = hs;
    ETs[(h + 0) * 40 + s] = h0;
    ETs[(h + 1) * 40 + s] = h1;
    ETs[(h + 2) * 40 + s] = h2;
    ETs[(h + 3) * 40 + s] = h3;
  }

  // Q fragments in registers: row m = mt*16+l15 -> t (clamped), 16 k-steps
  bf16x8 qa[16];
  {
    const int m = mt * 16 + l15;
    const int t = (m < NT + 1) ? m : NT;
    const float* qp = U + ((size_t)t * NB + b) * NH + quad * 8;
#pragma unroll
    for (int ks = 0; ks < 16; ++ks) {
      const float4 lo = *(const float4*)(qp + ks * 32);
      const float4 hi = *(const float4*)(qp + ks * 32 + 4);
      union { bf16x8 v; ushort u[8]; } pk;
      pk.u[0] = f2bf(lo.x); pk.u[1] = f2bf(lo.y); pk.u[2] = f2bf(lo.z); pk.u[3] = f2bf(lo.w);
      pk.u[4] = f2bf(hi.x); pk.u[5] = f2bf(hi.y); pk.u[6] = f2bf(hi.z); pk.u[7] = f2bf(hi.w);
      qa[ks] = pk.v;
    }
  }
  __syncthreads();

  // ---- QK^T : wave (mt,nt) computes a 16x16 S tile; B = row-major Erow ----
  f32x4 sacc = {0.f, 0.f, 0.f, 0.f};
#pragma unroll
  for (int ks = 0; ks < 16; ++ks) {
    const bf16x8 bf = *(const bf16x8*)&Erow[(nt * 16 + l15) * 520 + ks * 32 + quad * 8];
    sacc = __builtin_amdgcn_mfma_f32_16x16x32_bf16(qa[ks], bf, sacc, 0, 0, 0);
  }
#pragma unroll
  for (int r = 0; r < 4; ++r)
    S_lds[(mt * 16 + quad * 4 + r) * 33 + nt * 16 + l15] = sacc[r];
  __syncthreads();

  // ---- masked softmax over s (8 threads per row) ----
  {
    const int r = tid >> 3, c = tid & 7;
    const int base = b * NS + d * DL;
    float v0 = S_lds[r * 33 + c];
    if (numpairs[base + c] == 0) v0 = -1e9f;
    float v1 = S_lds[r * 33 + c + 8];
    if (numpairs[base + c + 8] == 0) v1 = -1e9f;
    float v2 = -1e30f;
    if (c < 4) {
      v2 = S_lds[r * 33 + c + 16];
      if (numpairs[base + c + 16] == 0) v2 = -1e9f;
    }
    float mx = fmaxf(fmaxf(v0, v1), v2);
    mx = fmaxf(mx, __shfl_xor(mx, 1));
    mx = fmaxf(mx, __shfl_xor(mx, 2));
    mx = fmaxf(mx, __shfl_xor(mx, 4));
    const float e0 = expf(v0 - mx), e1 = expf(v1 - mx);
    const float e2 = (c < 4) ? expf(v2 - mx) : 0.f;
    float sm = e0 + e1 + e2;
    sm += __shfl_xor(sm, 1);
    sm += __shfl_xor(sm, 2);
    sm += __shfl_xor(sm, 4);
    const float inv = 1.f / sm;
    P_lds[r * 40 + c] = f2bf(e0 * inv);
    P_lds[r * 40 + c + 8] = f2bf(e1 * inv);
    if (c < 4) P_lds[r * 40 + c + 16] = f2bf(e2 * inv);
  }
  __syncthreads();

  // ---- PV : wave (mt,nt) covers rows mt*16, h-cols nt*256 .. +255 ----
  const bf16x8 pa = *(const bf16x8*)&P_lds[(mt * 16 + l15) * 40 + quad * 8];
#pragma unroll
  for (int j = 0; j < 16; ++j) {
    const int hcol = nt * 256 + j * 16;
    const bf16x8 bf = *(const bf16x8*)&ETs[(hcol + l15) * 40 + quad * 8];
    f32x4 oacc = {0.f, 0.f, 0.f, 0.f};
    oacc = __builtin_amdgcn_mfma_f32_16x16x32_bf16(pa, bf, oacc, 0, 0, 0);
#pragma unroll
    for (int r = 0; r < 4; ++r) {
      const int t = mt * 16 + quad * 4 + r;
      if (t < NT)
        week[(((size_t)t * NB + b) * ND + d) * NH + hcol + l15] = f2bf(oacc[r]);
    }
  }
}

// ---------------------------------------------------------------------------
// Batched week attention + ctx + concat.  One block = (t, 16 b's).
// ---------------------------------------------------------------------------
__global__ __launch_bounds__(256) void wk_ctx(
    const float* __restrict__ U, const unsigned short* __restrict__ week,
    const float* __restrict__ H, unsigned short* __restrict__ concat)
{
  __shared__ float scS[16 * ND];
  __shared__ float awS[16 * ND];
  const int tid = threadIdx.x;
  const int t = blockIdx.x >> 5;
  const int grp = blockIdx.x & 31;
  const int b16 = tid >> 4, k16 = tid & 15;
  const int b = grp * 16 + b16;
  const float* vp = U + ((size_t)(t + 1) * NB + b) * NH + k16 * 32;
  const size_t wrow = ((size_t)t * NB + b) * ND;

  for (int d = 0; d < ND; ++d) {
    const unsigned short* wp = week + (wrow + d) * NH + k16 * 32;
    float p = 0.f;
#pragma unroll
    for (int q = 0; q < 8; ++q) {
      const float4 a = *(const float4*)(vp + q * 4);
      const ushort4 wv = *(const ushort4*)(wp + q * 4);
      p += a.x * bf2f(wv.x) + a.y * bf2f(wv.y) + a.z * bf2f(wv.z) + a.w * bf2f(wv.w);
    }
    p += __shfl_down(p, 8); p += __shfl_down(p, 4);
    p += __shfl_down(p, 2); p += __shfl_down(p, 1);
    if (k16 == 0) scS[b16 * ND + d] = p;
  }
  __syncthreads();
  if (tid < 16) {
    float s[ND], mx = -1e30f;
    for (int d = 0; d < ND; ++d) { s[d] = scS[tid * ND + d]; mx = fmaxf(mx, s[d]); }
    float sum = 0.f;
    for (int d = 0; d < ND; ++d) { float e = expf(s[d] - mx); s[d] = e; sum += e; }
    const float inv = 1.f / sum;
    for (int d = 0; d < ND; ++d) awS[tid * ND + d] = s[d] * inv;
  }
  __syncthreads();

  const int c0 = k16 * 32;
  const float* hp = H + ((size_t)(t + 1) * NB + b) * NH + c0;
  float aw[ND];
#pragma unroll
  for (int d = 0; d < ND; ++d) aw[d] = awS[b16 * ND + d];
  unsigned short* crow = concat + ((size_t)t * NB + b) * 1024;
#pragma unroll
  for (int q = 0; q < 8; ++q) {
    const int c = c0 + q * 4;
    const float4 hv = *(const float4*)(hp + q * 4);
    ushort4 hs;
    hs.x = f2bf(hv.x); hs.y = f2bf(hv.y); hs.z = f2bf(hv.z); hs.w = f2bf(hv.w);
    *(ushort4*)(crow + c) = hs;
    float4 cv = make_float4(0.f, 0.f, 0.f, 0.f);
#pragma unroll
    for (int d = 0; d < ND; ++d) {
      const ushort4 wv = *(const ushort4*)(week + (wrow + d) * NH + c);
      cv.x += aw[d] * bf2f(wv.x); cv.y += aw[d] * bf2f(wv.y);
      cv.z += aw[d] * bf2f(wv.z); cv.w += aw[d] * bf2f(wv.w);
    }
    ushort4 cs;
    cs.x = f2bf(cv.x); cs.y = f2bf(cv.y); cs.z = f2bf(cv.z); cs.w = f2bf(cv.w);
    *(ushort4*)(crow + 512 + c) = cs;
  }
}

// ---------------------------------------------------------------------------
// Single-pass log_softmax, row in registers.  Row r = t*NB+b -> out[b,t,:].
// ---------------------------------------------------------------------------
__global__ __launch_bounds__(256) void lsm_k(
    const float* __restrict__ logits, float* __restrict__ out)
{
  __shared__ float red[8];
  const int tid = threadIdx.x;
  const int wave = tid >> 6, lane = tid & 63;
  const int r = blockIdx.x;
  const int t = r >> 9, b = r & (NB - 1);
  const float* row = logits + (size_t)r * NVP;
  float v[4];
  float mx = -1e30f;
#pragma unroll
  for (int k = 0; k < 4; ++k) {
    const int c = tid + k * 256;
    v[k] = row[c];
    if (c < NV) mx = fmaxf(mx, v[k]);
  }
#pragma unroll
  for (int off = 32; off; off >>= 1) mx = fmaxf(mx, __shfl_xor(mx, off));
  if (lane == 0) red[wave] = mx;
  __syncthreads();
  mx = fmaxf(fmaxf(red[0], red[1]), fmaxf(red[2], red[3]));
  float s = 0.f;
#pragma unroll
  for (int k = 0; k < 4; ++k) {
    const int c = tid + k * 256;
    if (c < NV) s += expf(v[k] - mx);
  }
#pragma unroll
  for (int off = 32; off; off >>= 1) s += __shfl_xor(s, off);
  if (lane == 0) red[4 + wave] = s;
  __syncthreads();
  const float lse = mx + logf(red[4] + red[5] + red[6] + red[7]);
  float* orow = out + ((size_t)b * NT + t) * NV;
#pragma unroll
  for (int k = 0; k < 4; ++k) {
    const int c = tid + k * 256;
    if (c < NV) orow[c] = v[k] - lse;
  }
}

__global__ void write_last(const int* __restrict__ label, float* __restrict__ out2)
{
  const int b = blockIdx.x * 256 + threadIdx.x;
  if (b < NB) out2[b] = (float)label[b * LSTR + (NT - 1)];
}

// W1pk[(k/32)][n'][k%32]: n' = g*256 + gate*64 + (j - g*64); gate 0..2 =
// W_hh gates, gate 3 = Wa^T (u-gate).  k-chunked for coalesced staging.
__global__ __launch_bounds__(256) void pack_w1pk(
    const float* __restrict__ Whh, const float* __restrict__ Wa,
    unsigned short* __restrict__ W1pk)
{
  const int idx = blockIdx.x * 256 + threadIdx.x;
  const int np = idx >> 9, k = idx & 511;
  const int g = np >> 8, rem = np & 255, gate = rem >> 6, j = g * 64 + (rem & 63);
  float v;
  if (gate < 3) v = Whh[(size_t)(gate * 512 + j) * 512 + k];
  else          v = Wa[(size_t)k * 512 + j];
  W1pk[((size_t)(k >> 5) * 2048 + np) * 32 + (k & 31)] = f2bf(v);
}

__global__ __launch_bounds__(256) void cast4(
    const float4* __restrict__ in, ushort4* __restrict__ out, int n4)
{
  const int i = blockIdx.x * 256 + threadIdx.x;
  if (i < n4) {
    const float4 x = in[i];
    ushort4 r;
    r.x = f2bf(x.x); r.y = f2bf(x.y); r.z = f2bf(x.z); r.w = f2bf(x.w);
    out[i] = r;
  }
}

extern "C" void kernel_launch(void* const* d_in, const int* in_sizes, int n_in,
                              void* d_out, int out_size, void* d_ws, size_t ws_size,
                              hipStream_t stream)
{
  const float* enc_h  = (const float*)d_in[0];
  const float* enc    = (const float*)d_in[1];
  const int*   label  = (const int*)d_in[2];
  const int*   numprs = (const int*)d_in[3];
  const float* emb    = (const float*)d_in[4];
  const float* W_ih   = (const float*)d_in[5];
  const float* W_hh   = (const float*)d_in[6];
  const float* b_ih   = (const float*)d_in[7];
  const float* b_hh   = (const float*)d_in[8];
  const float* Wa     = (const float*)d_in[9];
  const float* wa_W   = (const float*)d_in[10];
  const float* fc_W   = (const float*)d_in[11];
  const float* fc_b   = (const float*)d_in[12];
  float* out = (float*)d_out;

  float* f = (float*)d_ws;
  float* H_all   = f; f += (size_t)(NT + 1) * NB * NH;   // 22 hidden states
  float* U_all   = f; f += (size_t)(NT + 1) * NB * NH;   // h_t @ Wa, all t
  float* logitsW = f; f += (size_t)NROW * NVP;
  unsigned short* us = (unsigned short*)f;
  unsigned short* W1pk   = us; us += (size_t)2048 * 512;
  unsigned short* W3t    = us; us += (size_t)512 * 1024;
  unsigned short* W4t    = us; us += (size_t)NVP * 512;
  unsigned short* Wiht   = us; us += (size_t)1536 * 256;
  unsigned short* Gi     = us; us += (size_t)NT * NB * 1536;
  unsigned short* week   = us; us += (size_t)NT * NB * ND * NH;
  unsigned short* concatW= us; us += (size_t)NROW * 1024;
  unsigned short* aBuf   = us; us += (size_t)NROW * 512;

  const dim3 blk(256);
  const size_t BH = (size_t)NB * NH;

  hipMemcpyAsync(H_all, enc_h, BH * sizeof(float),
                 hipMemcpyDeviceToDevice, stream);

  // --- setup: weight packs/casts + Gi precompute ---
  pack_w1pk<<<dim3(2048 * 512 / 256), blk, 0, stream>>>(W_hh, Wa, W1pk);
  cast4<<<dim3(512 * 1024 / 4 / 256), blk, 0, stream>>>(
      (const float4*)wa_W, (ushort4*)W3t, 512 * 1024 / 4);
  cast4<<<dim3((NV * 512 / 4 + 255) / 256), blk, 0, stream>>>(
      (const float4*)fc_W, (ushort4*)W4t, NV * 512 / 4);
  hipMemsetAsync(W4t + (size_t)NV * 512, 0, (size_t)(NVP - NV) * 512 * 2, stream);
  cast4<<<dim3(1536 * 256 / 4 / 256), blk, 0, stream>>>(
      (const float4*)W_ih, (ushort4*)Wiht, 1536 * 256 / 4);
  gemm_gather<<<dim3(24, NT * 8), blk, 0, stream>>>(emb, Wiht, Gi, label);

  // --- recurrent phase: fused GEMM+GRU, one kernel per step ---
  // t = NT runs u-only (produces U_all[21] for week attention).
  for (int t = 0; t <= NT; ++t) {
    const int notLast = (t < NT) ? 1 : 0;
    const int tg = (t < NT) ? t : NT - 1;   // Gi index (unused when last)
    step_fused<<<dim3(8, 16), blk, 0, stream>>>(
        H_all + (size_t)t * BH, W1pk, Gi + (size_t)tg * NB * 1536,
        b_ih, b_hh,
        H_all + (size_t)(notLast ? t + 1 : t) * BH,
        U_all + (size_t)t * BH, notLast);
  }

  // --- batched tail ---
  day_attn_mfma<<<dim3(NB * ND), blk, 0, stream>>>(enc, numprs, U_all, week);
  wk_ctx<<<dim3(NT * 32), blk, 0, stream>>>(U_all, week, H_all, concatW);
  gemm_k<1, 2, 1><<<dim3(8, NROW / 64), blk, 0, stream>>>(
      nullptr, concatW, W3t, nullptr, nullptr, aBuf, 1024, 1024, 512);
  gemm_k<1, 1, 0><<<dim3(16, NROW / 64), blk, 0, stream>>>(
      nullptr, aBuf, W4t, fc_b, logitsW, nullptr, 512, 512, NVP);
  lsm_k<<<dim3(NROW), blk, 0, stream>>>(logitsW, out);
  write_last<<<dim3(2), blk, 0, stream>>>(label, out + (size_t)NB * NT * NV);
}